// Round 3
// baseline (572.192 us; speedup 1.0000x reference)
//
#include <hip/hip_runtime.h>

// out[t, 0, d] = inputs[t, d]
// out[t, l, d] = memory[l, d]   (l = 1..L-1)
// T=2048, L=64, D=1024, fp32. Write-BW bound (512 MiB stores, ~8.3 MiB reads).
//
// R1: grid-stride loop (32 float4/thread, 4096 blocks) instead of
// one-store-per-thread over 131k workgroups — R0 was workgroup-dispatch-rate
// bound (~243 WG/us needed, 4 KiB work/WG).
// R2: native ext_vector_type(4) instead of HIP float4 so
// __builtin_nontemporal_store compiles (HIP_vector_type is a struct, rejected).

typedef float floatx4 __attribute__((ext_vector_type(4)));

constexpr int T = 2048;
constexpr int L = 64;
constexpr int D = 1024;
constexpr int N4 = T * L * D / 4;   // 33,554,432 float4s

__global__ __launch_bounds__(256) void sliding_window_memory_kernel(
    const floatx4* __restrict__ in,    // [T, D/4]   D/4 = 256
    const floatx4* __restrict__ mem,   // [L, D/4]   L*D/4 = 16384
    floatx4* __restrict__ out)         // [T, L, D/4]
{
    const int stride = gridDim.x * blockDim.x;
    for (int i = blockIdx.x * blockDim.x + threadIdx.x; i < N4; i += stride) {
        const int t   = i >> 14;        // / (L*D/4)
        const int rem = i & 16383;      // l*256 + d4
        floatx4 v;
        if (rem < 256) {                // l == 0 -> this step's input row
            v = in[(t << 8) + rem];
        } else {                        // l >= 1 -> frozen memory tail
            v = mem[rem];
        }
        __builtin_nontemporal_store(v, &out[i]);
    }
}

extern "C" void kernel_launch(void* const* d_in, const int* in_sizes, int n_in,
                              void* d_out, int out_size, void* d_ws, size_t ws_size,
                              hipStream_t stream) {
    const floatx4* in  = (const floatx4*)d_in[0];   // inputs [T, D] fp32
    const floatx4* mem = (const floatx4*)d_in[1];   // memory [L, D] fp32
    floatx4* out = (floatx4*)d_out;                 // [T, L, D] fp32

    // 4096 blocks x 256 threads = 1,048,576 threads, 32 float4 each.
    const int block = 256;
    const int grid  = 4096;
    sliding_window_memory_kernel<<<grid, block, 0, stream>>>(in, mem, out);
}

// Round 4
// 570.386 us; speedup vs baseline: 1.0032x; 1.0032x over previous
//
#include <hip/hip_runtime.h>

// out[t, 0, d] = inputs[t, d]
// out[t, l, d] = memory[l, d]   (l = 1..L-1)
// T=2048, L=64, D=1024, fp32. Write-BW bound (512 MiB stores, ~8.3 MiB reads).
//
// R1: grid-stride (R0 one-store-per-thread: 539 us bench).
// R3: + nontemporal stores -> 572 us. REGRESSION: nt bypasses L2 and defeats
//     write-combining of 16B stores into HBM bursts. Reverted.
// R4: grid-stride WITHOUT nt. Stride = 4096*256 = 1,048,576 = 64 slabs of
//     16384, so each thread's slab-offset `rem` is loop-invariant:
//     mem-lanes load their value ONCE and store it 32 times (explicitly
//     hoisted); in-lanes re-load per t. Branch is wave-uniform.

typedef float floatx4 __attribute__((ext_vector_type(4)));

constexpr int T = 2048;
constexpr int L = 64;
constexpr int D = 1024;
constexpr int N4 = T * L * D / 4;   // 33,554,432 float4s

__global__ __launch_bounds__(256) void sliding_window_memory_kernel(
    const floatx4* __restrict__ in,    // [T, D/4]   D/4 = 256
    const floatx4* __restrict__ mem,   // [L, D/4]   L*D/4 = 16384
    floatx4* __restrict__ out)         // [T, L, D/4]
{
    const int stride = gridDim.x * blockDim.x;       // 1,048,576 = 64*16384
    const int i0  = blockIdx.x * blockDim.x + threadIdx.x;
    const int rem = i0 & 16383;                      // loop-invariant slab offset
    const bool is_in = (rem < 256);                  // wave-uniform

    floatx4 v;
    if (!is_in) v = mem[rem];                        // frozen tail: load once

    for (int i = i0; i < N4; i += stride) {
        if (is_in) v = in[((i >> 14) << 8) + rem];   // this step's input row
        out[i] = v;
    }
}

extern "C" void kernel_launch(void* const* d_in, const int* in_sizes, int n_in,
                              void* d_out, int out_size, void* d_ws, size_t ws_size,
                              hipStream_t stream) {
    const floatx4* in  = (const floatx4*)d_in[0];   // inputs [T, D] fp32
    const floatx4* mem = (const floatx4*)d_in[1];   // memory [L, D] fp32
    floatx4* out = (floatx4*)d_out;                 // [T, L, D] fp32

    // 4096 blocks x 256 threads; stride stays a multiple of 16384 so `rem`
    // is loop-invariant per thread. 32 float4 stores per thread.
    const int block = 256;
    const int grid  = 4096;
    sliding_window_memory_kernel<<<grid, block, 0, stream>>>(in, mem, out);
}

// Round 5
// 551.032 us; speedup vs baseline: 1.0384x; 1.0351x over previous
//
#include <hip/hip_runtime.h>

// out[t, 0, d] = inputs[t, d]
// out[t, l, d] = memory[l, d]   (l = 1..L-1)
// T=2048, L=64, D=1024, fp32. Write-BW bound (512 MiB stores, ~8.3 MiB reads).
//
// R0: flat one-float4-per-thread, 131k WGs -> 539 us (best).
// R3/R4: grid-stride x32 loop (w/ and w/o nt) -> ~571 us. Regression is the
//   loop-carried load->store chain in the in-lanes (compiler can't unroll,
//   32 serialized HBM round trips), NOT the nt flag (R3==R4).
// R5: flat shape + explicit 8-way ILP. Each thread does 8 INDEPENDENT stores
//   spaced NTHREADS apart (multiple of 16384 -> rem/is_in loop-invariant,
//   wave-uniform). in-lanes issue all 8 loads up front; mem-lanes load once,
//   store 8x (cuts the L2 re-read stream 8x). WGs 131k -> 16k.

typedef float floatx4 __attribute__((ext_vector_type(4)));

constexpr int T = 2048;
constexpr int L = 64;
constexpr int D = 1024;
constexpr int N4 = T * L * D / 4;          // 33,554,432 float4s
constexpr int UNROLL = 8;
constexpr int NTHREADS = N4 / UNROLL;      // 4,194,304 = 256 * 16384  ✓

__global__ __launch_bounds__(256) void sliding_window_memory_kernel(
    const floatx4* __restrict__ in,    // [T, D/4]   D/4 = 256
    const floatx4* __restrict__ mem,   // [L, D/4]   L*D/4 = 16384
    floatx4* __restrict__ out)         // [T, L, D/4]
{
    const int tid = blockIdx.x * blockDim.x + threadIdx.x;   // < NTHREADS
    const int rem = tid & 16383;            // slab offset, same for all 8 stores
    const bool is_in = (rem < 256);         // wave-uniform (256-thread rows)

    floatx4 v[UNROLL];
    if (is_in) {
        #pragma unroll
        for (int k = 0; k < UNROLL; ++k) {
            const int i = tid + k * NTHREADS;
            v[k] = in[((i >> 14) << 8) + rem];   // 8 independent loads
        }
    } else {
        const floatx4 m = mem[rem];              // one L2 read, 8 stores
        #pragma unroll
        for (int k = 0; k < UNROLL; ++k) v[k] = m;
    }

    #pragma unroll
    for (int k = 0; k < UNROLL; ++k)
        out[tid + k * NTHREADS] = v[k];          // 8 independent stores
}

extern "C" void kernel_launch(void* const* d_in, const int* in_sizes, int n_in,
                              void* d_out, int out_size, void* d_ws, size_t ws_size,
                              hipStream_t stream) {
    const floatx4* in  = (const floatx4*)d_in[0];   // inputs [T, D] fp32
    const floatx4* mem = (const floatx4*)d_in[1];   // memory [L, D] fp32
    floatx4* out = (floatx4*)d_out;                 // [T, L, D] fp32

    const int block = 256;
    const int grid  = NTHREADS / block;             // 16,384
    sliding_window_memory_kernel<<<grid, block, 0, stream>>>(in, mem, out);
}